// Round 19
// baseline (121.970 us; speedup 1.0000x reference)
//
#include <hip/hip_runtime.h>

typedef unsigned short u16;
typedef unsigned int u32;
typedef __attribute__((ext_vector_type(8))) short bf16x8;
typedef __attribute__((ext_vector_type(4))) float f32x4;

__device__ __forceinline__ u16 f2bf(float f) {          // full RNE
    union { float f; u32 u; } x; x.f = f;
    u32 r = x.u + 0x7FFFu + ((x.u >> 16) & 1u);
    return (u16)(r >> 16);
}

__device__ __forceinline__ u16 f2bf_fast(float f) {     // round-half-up (hot path)
    union { float f; u32 u; } x; x.f = f;
    return (u16)((x.u + 0x8000u) >> 16);
}

__device__ __forceinline__ float bf2f(u16 v) {
    union { u32 u; float f; } x; x.u = (u32)v << 16; return x.f;
}

__device__ __forceinline__ void gload16(const u16* g, u16* l) {
    __builtin_amdgcn_global_load_lds(
        (const __attribute__((address_space(1))) void*)g,
        (__attribute__((address_space(3))) void*)l,
        16, 0, 0);
}

__device__ __forceinline__ f32x4 mfma16(bf16x8 a, bf16x8 b, f32x4 c) {
    return __builtin_amdgcn_mfma_f32_16x16x32_bf16(a, b, c, 0, 0, 0);
}

// ---------------- prep kernels ----------------

__global__ __launch_bounds__(256) void cvt_x(const float* __restrict__ in, u16* __restrict__ out, int n4) {
    int i = blockIdx.x * blockDim.x + threadIdx.x;
    if (i >= n4) return;
    float4 v = ((const float4*)in)[i];
    u16* o = out + (size_t)i * 4;
    o[0] = f2bf(v.x); o[1] = f2bf(v.y); o[2] = f2bf(v.z); o[3] = f2bf(v.w);
}

// all 4 weights in one launch; z selects the matrix. Block (z=3,x=0,y=0) also packs biases.
__global__ __launch_bounds__(256) void transpose_w4(const float* __restrict__ Wq, const float* __restrict__ Wk,
                                                    const float* __restrict__ Wv, const float* __restrict__ Wo,
                                                    const float* __restrict__ bq, const float* __restrict__ bk,
                                                    const float* __restrict__ bv,
                                                    u16* __restrict__ qkvt, u16* __restrict__ wot,
                                                    float* __restrict__ bqkv) {
    __shared__ float tile[32][33];
    const float* in;
    u16* out;
    if (blockIdx.z == 0)      { in = Wq; out = qkvt; }
    else if (blockIdx.z == 1) { in = Wk; out = qkvt + 1024 * 1024; }
    else if (blockIdx.z == 2) { in = Wv; out = qkvt + 2 * 1024 * 1024; }
    else                      { in = Wo; out = wot; }
    if (blockIdx.z == 3 && blockIdx.x == 0 && blockIdx.y == 0) {
        for (int i = threadIdx.x; i < 3072; i += 256)
            bqkv[i] = (i < 1024) ? bq[i] : ((i < 2048) ? bk[i - 1024] : bv[i - 2048]);
    }
    const int bx = blockIdx.x * 32, by = blockIdx.y * 32;
    const int tx = threadIdx.x & 31, ty4 = (threadIdx.x >> 5) * 4;
#pragma unroll
    for (int j = 0; j < 4; ++j)
        tile[ty4 + j][tx] = in[(size_t)(by + ty4 + j) * 1024 + bx + tx];
    __syncthreads();
#pragma unroll
    for (int j = 0; j < 4; ++j)
        out[(size_t)(bx + ty4 + j) * 1024 + by + tx] = f2bf(tile[tx][ty4 + j]);
}

// ---------------- QKV GEMM: 128^2 tile, BK=64, XCD-swizzled 1D grid, RUNTIME K ----------------
// (R18-proven: runtime K keeps VGPR ~80 / occupancy ~27%; compile-time K bloated to 108-116.)
__global__ __launch_bounds__(256) void gemm128_qkv(const u16* __restrict__ A, const u16* __restrict__ Bt,
                                                   const float* __restrict__ bias,
                                                   u16* __restrict__ oq, u16* __restrict__ ok,
                                                   u16* __restrict__ ov, int K)
{
    __shared__ u16 As[128 * 64];
    __shared__ u16 Bs[128 * 64];

    const int NB = 24, CHUNK = 96;              // nwg = 768
    const int f = (int)blockIdx.x;
    const int g2 = (f & 7) * CHUNK + (f >> 3);  // bijective XCD swizzle
    const int n0 = (g2 % NB) * 128;
    const int m0 = (g2 / NB) * 128;

    const int t = threadIdx.x;
    const int w = t >> 6, lane = t & 63;
    const int g = lane >> 4, lr = lane & 15;
    const int wm = w >> 1, wn = w & 1;
    const int sw = lr & 7;

    const int srow = lane >> 3;
    const int schunk = (lane & 7) ^ srow;       // pre-swizzled global source
    const u16* pA = A  + (size_t)(m0 + w * 8 + srow) * K + schunk * 8;
    const u16* pB = Bt + (size_t)(n0 + w * 8 + srow) * K + schunk * 8;
    u16* lA = &As[w * 512 + lane * 8];
    u16* lB = &Bs[w * 512 + lane * 8];

    const int sa_row = (wm * 64 + lr) * 64;
    const int sb_row = (wn * 64 + lr) * 64;

    f32x4 acc[4][4] = {};

    for (int k0 = 0; k0 < K; k0 += 64) {
        __syncthreads();
#pragma unroll
        for (int i = 0; i < 4; ++i) {
            gload16(pA + (size_t)i * 32 * K + k0, lA + i * 2048);
            gload16(pB + (size_t)i * 32 * K + k0, lB + i * 2048);
        }
        __syncthreads();
#pragma unroll
        for (int kk = 0; kk < 2; ++kk) {
            const int cofs = ((kk * 4 + g) ^ sw) * 8;
            bf16x8 af[4], bf[4];
#pragma unroll
            for (int mi = 0; mi < 4; ++mi) af[mi] = *(const bf16x8*)&As[sa_row + mi * 16 * 64 + cofs];
#pragma unroll
            for (int ni = 0; ni < 4; ++ni) bf[ni] = *(const bf16x8*)&Bs[sb_row + ni * 16 * 64 + cofs];
#pragma unroll
            for (int mi = 0; mi < 4; ++mi)
#pragma unroll
                for (int ni = 0; ni < 4; ++ni)
                    acc[mi][ni] = mfma16(af[mi], bf[ni], acc[mi][ni]);
        }
    }

#pragma unroll
    for (int mi = 0; mi < 4; ++mi) {
#pragma unroll
        for (int ni = 0; ni < 4; ++ni) {
            const int col = n0 + wn * 64 + ni * 16 + lr;
            const int row0 = m0 + wm * 64 + mi * 16 + g * 4;
            const float bs = bias[col];
            const int mat = col >> 10;
            const int nn = col & 1023;
            const int h = nn >> 6, d = nn & 63;
            const int b = row0 >> 11, ll0 = row0 & 2047;
            const int bh = b * 16 + h;
            if (mat == 0) {
#pragma unroll
                for (int j = 0; j < 4; ++j)
                    oq[((size_t)bh * 2048 + ll0 + j) * 64 + d] =
                        f2bf((acc[mi][ni][j] + bs) * 0.1803368801111244f);  // (1/8)*log2(e)
            } else if (mat == 1) {
#pragma unroll
                for (int j = 0; j < 4; ++j)
                    ok[((size_t)bh * 2048 + ll0 + j) * 64 + d] = f2bf(acc[mi][ni][j] + bs);
            } else {
                union { ushort4 s4; u16 u[4]; } pk;
#pragma unroll
                for (int j = 0; j < 4; ++j) pk.u[j] = f2bf(acc[mi][ni][j] + bs);
                *(ushort4*)&ov[((size_t)bh * 64 + d) * 2048 + ll0] = pk.s4;
            }
        }
    }
}

// ---------------- O-projection GEMM: 64x128 tile (512 blocks = 2/CU), runtime K ----------------
__global__ __launch_bounds__(256) void gemm_o(const u16* __restrict__ A, const u16* __restrict__ Bt,
                                              const float* __restrict__ bias, float* __restrict__ of,
                                              int K)
{
    __shared__ u16 As[64 * 64];     // 8 KB
    __shared__ u16 Bs[128 * 64];    // 16 KB

    const int n0 = blockIdx.x * 128;     // 8 n-blocks
    const int m0 = blockIdx.y * 64;      // 64 m-blocks
    const int t = threadIdx.x;
    const int w = t >> 6, lane = t & 63;
    const int g = lane >> 4, lr = lane & 15;
    const int sw = lr & 7;
    const int wn = w;                    // wave owns cols [wn*32, +32)

    const int srow8 = t >> 3;            // 0..31
    const int sch = t & 7;
    const int schunk = sch ^ (srow8 & 7);
    const u16* pA = A  + (size_t)(m0 + srow8) * K + schunk * 8;
    const u16* pB = Bt + (size_t)(n0 + srow8) * K + schunk * 8;
    const int ldst = srow8 * 64 + sch * 8;   // == w*512 + lane*8

    f32x4 acc[4][2] = {};

    for (int k0 = 0; k0 < K; k0 += 64) {
        __syncthreads();
#pragma unroll
        for (int i = 0; i < 2; ++i)
            gload16(pA + (size_t)(i * 32) * K + k0, &As[i * 2048 + ldst]);
#pragma unroll
        for (int i = 0; i < 4; ++i)
            gload16(pB + (size_t)(i * 32) * K + k0, &Bs[i * 2048 + ldst]);
        __syncthreads();
#pragma unroll
        for (int kk = 0; kk < 2; ++kk) {
            const int cofs = ((kk * 4 + g) ^ sw) * 8;
            bf16x8 af[4], bf[2];
#pragma unroll
            for (int mi = 0; mi < 4; ++mi) af[mi] = *(const bf16x8*)&As[(mi * 16 + lr) * 64 + cofs];
#pragma unroll
            for (int ni = 0; ni < 2; ++ni) bf[ni] = *(const bf16x8*)&Bs[(wn * 32 + ni * 16 + lr) * 64 + cofs];
#pragma unroll
            for (int mi = 0; mi < 4; ++mi)
#pragma unroll
                for (int ni = 0; ni < 2; ++ni)
                    acc[mi][ni] = mfma16(af[mi], bf[ni], acc[mi][ni]);
        }
    }

#pragma unroll
    for (int mi = 0; mi < 4; ++mi)
#pragma unroll
        for (int ni = 0; ni < 2; ++ni) {
            const int col = n0 + wn * 32 + ni * 16 + lr;
            const int row0 = m0 + mi * 16 + g * 4;
            const float bs = bias[col];
#pragma unroll
            for (int j = 0; j < 4; ++j)
                of[(size_t)(row0 + j) * 1024 + col] = acc[mi][ni][j] + bs;
        }
}

// ---------------- flash attention (causal): swapped QK^T, deferred-PV pipeline ----------------
// Q,K: [32 bh][2048][64] bf16 (Q pre-scaled by log2e/8).  Vt: [32 bh][64][2048] bf16.
// R19: one-tile-deferred PV (T15-analog). Tile t's P fragments stay in registers; at tile
// t+1, QK(t+1) MFMAs issue first, PV(t) MFMAs (independent) fill the QK latency shadow, and
// softmax(t+1) VALU runs under PV(t)'s MFMA latency. V is double-buffered (Vs[2]) so PV(t)
// can read tile t's V after tile t+1's commit; K stays single-buffered (consumed in-tile).
// Rescale stays exact: PV(t) lands in oacc BEFORE tile t+1's defer-max rescale.
__global__ __launch_bounds__(256) void attn(const u16* __restrict__ Q, const u16* __restrict__ Kg,
                                            const u16* __restrict__ Vt, u16* __restrict__ O,
                                            u16* __restrict__ Opart, float* __restrict__ Mp,
                                            float* __restrict__ Lp, int do_split)
{
    __shared__ u16 Ks[64 * 64];          // 8 KB
    __shared__ u16 Vs[2][64 * 64];       // 16 KB (dbuf for deferred PV)
    __shared__ u16 Ps[4][16 * 64];       // 8 KB, per-wave P tile, chunk-swizzled

    const int bh = blockIdx.x;
    int qb, k_lo, k_hi, split;
    if (!do_split) {
        qb = 31 - (int)blockIdx.y; k_lo = 0; k_hi = qb + 1; split = -1;
    } else {
        const int y = (int)blockIdx.y;
        if (y < 32) {                    // split blocks dispatch first (heaviest work)
            qb = 16 + (y >> 1);
            split = y & 1;
            const int mid = (qb + 1) >> 1;
            k_lo = split ? mid : 0;
            k_hi = split ? qb + 1 : mid;
        } else {
            qb = 47 - y; k_lo = 0; k_hi = qb + 1; split = -1;
        }
    }
    const int q0 = qb * 64;
    const int t = threadIdx.x;
    const int w = t >> 6, lane = t & 63;
    const int g = lane >> 4, lr = lane & 15;
    const int qw = q0 + w * 16;
    const int sw = lr & 7;

    const u16* Qb = Q  + (size_t)bh * 2048 * 64;
    const u16* Kb = Kg + (size_t)bh * 2048 * 64;
    const u16* Vb = Vt + (size_t)bh * 64 * 2048;

    const bf16x8 qf0 = *(const bf16x8*)&Qb[(size_t)(qw + lr) * 64 + g * 8];
    const bf16x8 qf1 = *(const bf16x8*)&Qb[(size_t)(qw + lr) * 64 + 32 + g * 8];

    const short one = (short)0x3F80;                 // bf16 1.0
    const bf16x8 vones = {one, one, one, one, one, one, one, one};

    f32x4 oacc[4] = {};                              // C layout: q = qw + 4g+j, d = df*16+lr
    f32x4 lsacc = {};                                // row sums (P @ ones), same layout
    float mrun = -1e30f;                             // softmax state for q = qw + lr

    int bpaddr[4];
#pragma unroll
    for (int j = 0; j < 4; ++j) bpaddr[j] = (20 * g + j) * 4;

    const int pw_base = lr * 64;
    const int g2h = g >> 1;
    const int wic2 = (2 * g) & 3;

    bf16x8 kreg[2], vreg[2];
    const int srow0 = t >> 3, sch = t & 7;
    auto issue = [&](int kb) {
#pragma unroll
        for (int i = 0; i < 2; ++i) {
            const int row = srow0 + i * 32;
            kreg[i] = *(const bf16x8*)&Kb[(size_t)(kb * 64 + row) * 64 + sch * 8];
            vreg[i] = *(const bf16x8*)&Vb[(size_t)row * 2048 + kb * 64 + sch * 8];
        }
    };
    auto commit = [&](int vbuf) {
#pragma unroll
        for (int i = 0; i < 2; ++i) {
            const int row = srow0 + i * 32;
            const int chs = sch ^ (row & 7);
            *(bf16x8*)&Ks[row * 64 + chs * 8] = kreg[i];
            *(bf16x8*)&Vs[vbuf][row * 64 + chs * 8] = vreg[i];
        }
    };

    issue(k_lo);

    bf16x8 pp0, pp1;                     // previous tile's P fragments (deferred PV)

    for (int kb = k_lo; kb < k_hi; ++kb) {
        const int vb = (kb - k_lo) & 1;
        const int k0 = kb * 64;
        __syncthreads();                 // all waves done with Ks(kb-1) and Vs[vb](kb-2)
        commit(vb);                      // regs -> Ks, Vs[vb]
        __syncthreads();                 // publish tile kb
        if (kb + 1 < k_hi) issue(kb + 1);

        // ---- QK(kb) MFMAs first: S^T = K @ Q^T, lane holds S[q=qw+lr][kloc=16ni+4g+j] ----
        f32x4 s[4] = {};
        __builtin_amdgcn_s_setprio(1);
#pragma unroll
        for (int ni = 0; ni < 4; ++ni) {
            const int row = ni * 16 + lr;
            bf16x8 kf0 = *(const bf16x8*)&Ks[row * 64 + (g ^ sw) * 8];
            bf16x8 kf1 = *(const bf16x8*)&Ks[row * 64 + ((4 + g) ^ sw) * 8];
            s[ni] = mfma16(kf0, qf0, s[ni]);
            s[ni] = mfma16(kf1, qf1, s[ni]);
        }
        // ---- deferred PV(kb-1): independent of s, fills QK latency shadow ----
        if (kb > k_lo) {
            lsacc = mfma16(pp0, vones, lsacc);
            lsacc = mfma16(pp1, vones, lsacc);
            const u16* vprev = Vs[vb ^ 1];
#pragma unroll
            for (int df = 0; df < 4; ++df) {
                const int row = df * 16 + lr;
                bf16x8 vf0 = *(const bf16x8*)&vprev[row * 64 + (g ^ sw) * 8];
                bf16x8 vf1 = *(const bf16x8*)&vprev[row * 64 + ((4 + g) ^ sw) * 8];
                oacc[df] = mfma16(pp0, vf0, oacc[df]);
                oacc[df] = mfma16(pp1, vf1, oacc[df]);
            }
        }
        __builtin_amdgcn_s_setprio(0);

        if (kb == qb) {                  // diagonal tile: causal mask (k > q)
            const int qq = qw + lr;
#pragma unroll
            for (int ni = 0; ni < 4; ++ni)
#pragma unroll
                for (int j = 0; j < 4; ++j)
                    if (k0 + ni * 16 + g * 4 + j > qq) s[ni][j] = -1e30f;
        }

        // ---- row max: 15 in-lane fmax + 2 shfl ----
        float pm = fmaxf(fmaxf(fmaxf(s[0][0], s[0][1]), fmaxf(s[0][2], s[0][3])),
                         fmaxf(fmaxf(s[1][0], s[1][1]), fmaxf(s[1][2], s[1][3])));
        pm = fmaxf(pm, fmaxf(fmaxf(fmaxf(s[2][0], s[2][1]), fmaxf(s[2][2], s[2][3])),
                             fmaxf(fmaxf(s[3][0], s[3][1]), fmaxf(s[3][2], s[3][3]))));
        pm = fmaxf(pm, __shfl_xor(pm, 16));
        pm = fmaxf(pm, __shfl_xor(pm, 32));

        // ---- defer-max (T13, THR=8): rescale AFTER PV(kb-1) has landed in oacc ----
        if (__any(pm > mrun + 8.f)) {
            const float mn = fmaxf(mrun, pm);
            const float r = __builtin_amdgcn_exp2f(mrun - mn);
            mrun = mn;
            const int ri = __float_as_int(r);
#pragma unroll
            for (int j = 0; j < 4; ++j) {
                const float ro = __int_as_float(__builtin_amdgcn_ds_bpermute(bpaddr[j], ri));
                lsacc[j] *= ro;
#pragma unroll
                for (int df = 0; df < 4; ++df) oacc[df][j] *= ro;
            }
        }

        // ---- P = exp2(S - m): pack bf16 pairs and write to LDS (q,kloc) slots ----
#pragma unroll
        for (int ni = 0; ni < 4; ++ni) {
            const int c8 = 2 * ni + g2h;
#pragma unroll
            for (int jp = 0; jp < 2; ++jp) {
                const float plo = __builtin_amdgcn_exp2f(s[ni][2 * jp]     - mrun);
                const float phi = __builtin_amdgcn_exp2f(s[ni][2 * jp + 1] - mrun);
                const u32 pr = (u32)f2bf_fast(plo) | ((u32)f2bf_fast(phi) << 16);
                const int wic = wic2 + jp;
                *(u32*)&Ps[w][pw_base + (c8 ^ sw) * 8 + wic * 2] = pr;
            }
        }
        // P is per-wave private: lgkmcnt (compiler) orders write->read, no barrier

        // ---- load this tile's P fragments; consumed by PV at the next iteration ----
        pp0 = *(const bf16x8*)&Ps[w][lr * 64 + (g ^ sw) * 8];
        pp1 = *(const bf16x8*)&Ps[w][lr * 64 + ((4 + g) ^ sw) * 8];
    }

    // ---- flush: PV of the last tile ----
    {
        const int vb = (k_hi - 1 - k_lo) & 1;
        const u16* vlast = Vs[vb];
        __builtin_amdgcn_s_setprio(1);
        lsacc = mfma16(pp0, vones, lsacc);
        lsacc = mfma16(pp1, vones, lsacc);
#pragma unroll
        for (int df = 0; df < 4; ++df) {
            const int row = df * 16 + lr;
            bf16x8 vf0 = *(const bf16x8*)&vlast[row * 64 + (g ^ sw) * 8];
            bf16x8 vf1 = *(const bf16x8*)&vlast[row * 64 + ((4 + g) ^ sw) * 8];
            oacc[df] = mfma16(pp0, vf0, oacc[df]);
            oacc[df] = mfma16(pp1, vf1, oacc[df]);
        }
        __builtin_amdgcn_s_setprio(0);
    }

    if (split < 0) {
        // direct epilogue: normalize by MFMA row sums; store to [b][l][h*64+d]
        const int b = bh >> 4, h = bh & 15;
#pragma unroll
        for (int j = 0; j < 4; ++j) {
            const float inv = 1.f / lsacc[j];
            const int l = qw + g * 4 + j;
#pragma unroll
            for (int df = 0; df < 4; ++df)
                O[((size_t)b * 2048 + l) * 1024 + h * 64 + df * 16 + lr] = f2bf(oacc[df][j] * inv);
        }
    } else {
        // partial epilogue: bf16 NORMALIZED O + f32 per-row (m, l)
        u16* Ob = Opart + ((size_t)split * 32 + bh) * (1024 * 64);
        const int rb = qw - 1024 + 4 * g;            // block-relative row for (g,j)
#pragma unroll
        for (int j = 0; j < 4; ++j) {
            const float inv = 1.f / lsacc[j];
#pragma unroll
            for (int df = 0; df < 4; ++df)
                Ob[(size_t)(rb + j) * 64 + df * 16 + lr] = f2bf(oacc[df][j] * inv);
            if (lr == 0) Lp[(split * 32 + bh) * 1024 + rb + j] = lsacc[j];
        }
        if (g == 0)
            Mp[(split * 32 + bh) * 1024 + (qw - 1024) + lr] = mrun;
    }
}

// ---------------- merge of split-K partials (rows 1024..2047 of each bh) ----------------
__global__ __launch_bounds__(256) void attn_merge(const u16* __restrict__ Opart,
                                                  const float* __restrict__ Mp,
                                                  const float* __restrict__ Lp,
                                                  u16* __restrict__ O)
{
    const int idx = blockIdx.x * 256 + threadIdx.x;   // over 32*1024*64
    const int d  = idx & 63;
    const int rr = (idx >> 6) & 1023;
    const int bh = idx >> 16;
    const int si = bh * 1024 + rr;
    const float m0 = Mp[si], m1 = Mp[32 * 1024 + si];
    const float l0 = Lp[si], l1 = Lp[32 * 1024 + si];
    const float M  = fmaxf(m0, m1);
    const float v0 = __builtin_amdgcn_exp2f(m0 - M) * l0;
    const float v1 = __builtin_amdgcn_exp2f(m1 - M) * l1;
    const float o0 = bf2f(Opart[(size_t)si * 64 + d]);
    const float o1 = bf2f(Opart[(size_t)(32 * 1024 + si) * 64 + d]);
    const float o  = (v0 * o0 + v1 * o1) / (v0 + v1);
    const int b = bh >> 4, h = bh & 15;
    const int r = 1024 + rr;
    O[((size_t)b * 2048 + r) * 1024 + h * 64 + d] = f2bf(o);
}

// ---------------- launch ----------------

extern "C" void kernel_launch(void* const* d_in, const int* in_sizes, int n_in,
                              void* d_out, int out_size, void* d_ws, size_t ws_size,
                              hipStream_t stream)
{
    const float* hs = (const float*)d_in[0];
    const float* Wq = (const float*)d_in[1];
    const float* bq = (const float*)d_in[2];
    const float* Wk = (const float*)d_in[3];
    const float* bk = (const float*)d_in[4];
    const float* Wv = (const float*)d_in[5];
    const float* bv = (const float*)d_in[6];
    const float* Wo = (const float*)d_in[7];
    const float* bo = (const float*)d_in[8];
    float* out = (float*)d_out;

    char* ws = (char*)d_ws;
    u16*   Xbf   = (u16*)(ws);                     // 8 MB, reused as Abuf after QKV GEMM
    u16*   Wqkvt = (u16*)(ws + (8ull  << 20));     // 6 MB
    u16*   Wot   = (u16*)(ws + (14ull << 20));     // 2 MB
    float* bqkv  = (float*)(ws + (16ull << 20));   // 12 KB
    u16*   Qbuf  = (u16*)(ws + (17ull << 20));     // 8 MB
    u16*   Kbuf  = (u16*)(ws + (25ull << 20));     // 8 MB
    u16*   Vtbuf = (u16*)(ws + (33ull << 20));     // 8 MB
    u16*   Abuf  = Xbf;                            // alias: X dead after QKV GEMM
    u16*   Opart = (u16*)(ws + (42ull << 20));     // 8 MB  [2 splits][32 bh][1024 r][64 d] bf16
    float* Mpart = (float*)(ws + (58ull << 20));   // 256 KB [2][32][1024]
    float* Lpart = (float*)(ws + (58ull << 20) + (512ull << 10));   // 256 KB

    const int do_split = (ws_size >= (59ull << 20)) ? 1 : 0;

    cvt_x<<<4096, 256, 0, stream>>>(hs, Xbf, 4096 * 1024 / 4);
    transpose_w4<<<dim3(32, 32, 4), 256, 0, stream>>>(Wq, Wk, Wv, Wo, bq, bk, bv, Wqkvt, Wot, bqkv);

    // QKV: [4096 x 3072], 1D grid with XCD swizzle, runtime K
    gemm128_qkv<<<768, 256, 0, stream>>>(Xbf, Wqkvt, bqkv, Qbuf, Kbuf, Vtbuf, 1024);

    // attention: two-half split for heavy q-blocks when workspace allows
    if (do_split) {
        attn<<<dim3(32, 48), 256, 0, stream>>>(Qbuf, Kbuf, Vtbuf, Abuf, Opart, Mpart, Lpart, 1);
        attn_merge<<<8192, 256, 0, stream>>>(Opart, Mpart, Lpart, Abuf);
    } else {
        attn<<<dim3(32, 32), 256, 0, stream>>>(Qbuf, Kbuf, Vtbuf, Abuf, nullptr, nullptr, nullptr, 0);
    }

    // output projection: [4096 x 1024] -> fp32 d_out, 64x128 tile (512 blocks, 2/CU), runtime K
    gemm_o<<<dim3(8, 64), 256, 0, stream>>>(Abuf, Wot, bo, out, 1024);
}

// Round 20
// 119.384 us; speedup vs baseline: 1.0217x; 1.0217x over previous
//
#include <hip/hip_runtime.h>

typedef unsigned short u16;
typedef unsigned int u32;
typedef __attribute__((ext_vector_type(8))) short bf16x8;
typedef __attribute__((ext_vector_type(4))) float f32x4;

__device__ __forceinline__ u16 f2bf(float f) {          // full RNE
    union { float f; u32 u; } x; x.f = f;
    u32 r = x.u + 0x7FFFu + ((x.u >> 16) & 1u);
    return (u16)(r >> 16);
}

__device__ __forceinline__ u16 f2bf_fast(float f) {     // round-half-up (hot path)
    union { float f; u32 u; } x; x.f = f;
    return (u16)((x.u + 0x8000u) >> 16);
}

__device__ __forceinline__ float bf2f(u16 v) {
    union { u32 u; float f; } x; x.u = (u32)v << 16; return x.f;
}

__device__ __forceinline__ void gload16(const u16* g, u16* l) {
    __builtin_amdgcn_global_load_lds(
        (const __attribute__((address_space(1))) void*)g,
        (__attribute__((address_space(3))) void*)l,
        16, 0, 0);
}

__device__ __forceinline__ f32x4 mfma16(bf16x8 a, bf16x8 b, f32x4 c) {
    return __builtin_amdgcn_mfma_f32_16x16x32_bf16(a, b, c, 0, 0, 0);
}

// ---------------- prep kernels ----------------

__global__ __launch_bounds__(256) void cvt_x(const float* __restrict__ in, u16* __restrict__ out, int n4) {
    int i = blockIdx.x * blockDim.x + threadIdx.x;
    if (i >= n4) return;
    float4 v = ((const float4*)in)[i];
    u16* o = out + (size_t)i * 4;
    o[0] = f2bf(v.x); o[1] = f2bf(v.y); o[2] = f2bf(v.z); o[3] = f2bf(v.w);
}

// all 4 weights in one launch; z selects the matrix. Block (z=3,x=0,y=0) also packs biases.
__global__ __launch_bounds__(256) void transpose_w4(const float* __restrict__ Wq, const float* __restrict__ Wk,
                                                    const float* __restrict__ Wv, const float* __restrict__ Wo,
                                                    const float* __restrict__ bq, const float* __restrict__ bk,
                                                    const float* __restrict__ bv,
                                                    u16* __restrict__ qkvt, u16* __restrict__ wot,
                                                    float* __restrict__ bqkv) {
    __shared__ float tile[32][33];
    const float* in;
    u16* out;
    if (blockIdx.z == 0)      { in = Wq; out = qkvt; }
    else if (blockIdx.z == 1) { in = Wk; out = qkvt + 1024 * 1024; }
    else if (blockIdx.z == 2) { in = Wv; out = qkvt + 2 * 1024 * 1024; }
    else                      { in = Wo; out = wot; }
    if (blockIdx.z == 3 && blockIdx.x == 0 && blockIdx.y == 0) {
        for (int i = threadIdx.x; i < 3072; i += 256)
            bqkv[i] = (i < 1024) ? bq[i] : ((i < 2048) ? bk[i - 1024] : bv[i - 2048]);
    }
    const int bx = blockIdx.x * 32, by = blockIdx.y * 32;
    const int tx = threadIdx.x & 31, ty4 = (threadIdx.x >> 5) * 4;
#pragma unroll
    for (int j = 0; j < 4; ++j)
        tile[ty4 + j][tx] = in[(size_t)(by + ty4 + j) * 1024 + bx + tx];
    __syncthreads();
#pragma unroll
    for (int j = 0; j < 4; ++j)
        out[(size_t)(bx + ty4 + j) * 1024 + by + tx] = f2bf(tile[tx][ty4 + j]);
}

// ---------------- QKV GEMM: 128^2 tile, BK=64, XCD-swizzled 1D grid, RUNTIME K ----------------
// (R18-proven: runtime K keeps VGPR ~80 / occupancy ~27%; compile-time K bloated to 108-116.)
__global__ __launch_bounds__(256) void gemm128_qkv(const u16* __restrict__ A, const u16* __restrict__ Bt,
                                                   const float* __restrict__ bias,
                                                   u16* __restrict__ oq, u16* __restrict__ ok,
                                                   u16* __restrict__ ov, int K)
{
    __shared__ u16 As[128 * 64];
    __shared__ u16 Bs[128 * 64];

    const int NB = 24, CHUNK = 96;              // nwg = 768
    const int f = (int)blockIdx.x;
    const int g2 = (f & 7) * CHUNK + (f >> 3);  // bijective XCD swizzle
    const int n0 = (g2 % NB) * 128;
    const int m0 = (g2 / NB) * 128;

    const int t = threadIdx.x;
    const int w = t >> 6, lane = t & 63;
    const int g = lane >> 4, lr = lane & 15;
    const int wm = w >> 1, wn = w & 1;
    const int sw = lr & 7;

    const int srow = lane >> 3;
    const int schunk = (lane & 7) ^ srow;       // pre-swizzled global source
    const u16* pA = A  + (size_t)(m0 + w * 8 + srow) * K + schunk * 8;
    const u16* pB = Bt + (size_t)(n0 + w * 8 + srow) * K + schunk * 8;
    u16* lA = &As[w * 512 + lane * 8];
    u16* lB = &Bs[w * 512 + lane * 8];

    const int sa_row = (wm * 64 + lr) * 64;
    const int sb_row = (wn * 64 + lr) * 64;

    f32x4 acc[4][4] = {};

    for (int k0 = 0; k0 < K; k0 += 64) {
        __syncthreads();
#pragma unroll
        for (int i = 0; i < 4; ++i) {
            gload16(pA + (size_t)i * 32 * K + k0, lA + i * 2048);
            gload16(pB + (size_t)i * 32 * K + k0, lB + i * 2048);
        }
        __syncthreads();
#pragma unroll
        for (int kk = 0; kk < 2; ++kk) {
            const int cofs = ((kk * 4 + g) ^ sw) * 8;
            bf16x8 af[4], bf[4];
#pragma unroll
            for (int mi = 0; mi < 4; ++mi) af[mi] = *(const bf16x8*)&As[sa_row + mi * 16 * 64 + cofs];
#pragma unroll
            for (int ni = 0; ni < 4; ++ni) bf[ni] = *(const bf16x8*)&Bs[sb_row + ni * 16 * 64 + cofs];
#pragma unroll
            for (int mi = 0; mi < 4; ++mi)
#pragma unroll
                for (int ni = 0; ni < 4; ++ni)
                    acc[mi][ni] = mfma16(af[mi], bf[ni], acc[mi][ni]);
        }
    }

#pragma unroll
    for (int mi = 0; mi < 4; ++mi) {
#pragma unroll
        for (int ni = 0; ni < 4; ++ni) {
            const int col = n0 + wn * 64 + ni * 16 + lr;
            const int row0 = m0 + wm * 64 + mi * 16 + g * 4;
            const float bs = bias[col];
            const int mat = col >> 10;
            const int nn = col & 1023;
            const int h = nn >> 6, d = nn & 63;
            const int b = row0 >> 11, ll0 = row0 & 2047;
            const int bh = b * 16 + h;
            if (mat == 0) {
#pragma unroll
                for (int j = 0; j < 4; ++j)
                    oq[((size_t)bh * 2048 + ll0 + j) * 64 + d] =
                        f2bf((acc[mi][ni][j] + bs) * 0.1803368801111244f);  // (1/8)*log2(e)
            } else if (mat == 1) {
#pragma unroll
                for (int j = 0; j < 4; ++j)
                    ok[((size_t)bh * 2048 + ll0 + j) * 64 + d] = f2bf(acc[mi][ni][j] + bs);
            } else {
                union { ushort4 s4; u16 u[4]; } pk;
#pragma unroll
                for (int j = 0; j < 4; ++j) pk.u[j] = f2bf(acc[mi][ni][j] + bs);
                *(ushort4*)&ov[((size_t)bh * 64 + d) * 2048 + ll0] = pk.s4;
            }
        }
    }
}

// ---------------- O-projection GEMM: 64x128 tile (512 blocks = 2/CU), runtime K ----------------
__global__ __launch_bounds__(256) void gemm_o(const u16* __restrict__ A, const u16* __restrict__ Bt,
                                              const float* __restrict__ bias, float* __restrict__ of,
                                              int K)
{
    __shared__ u16 As[64 * 64];     // 8 KB
    __shared__ u16 Bs[128 * 64];    // 16 KB

    const int n0 = blockIdx.x * 128;     // 8 n-blocks
    const int m0 = blockIdx.y * 64;      // 64 m-blocks
    const int t = threadIdx.x;
    const int w = t >> 6, lane = t & 63;
    const int g = lane >> 4, lr = lane & 15;
    const int sw = lr & 7;
    const int wn = w;                    // wave owns cols [wn*32, +32)

    const int srow8 = t >> 3;            // 0..31
    const int sch = t & 7;
    const int schunk = sch ^ (srow8 & 7);
    const u16* pA = A  + (size_t)(m0 + srow8) * K + schunk * 8;
    const u16* pB = Bt + (size_t)(n0 + srow8) * K + schunk * 8;
    const int ldst = srow8 * 64 + sch * 8;   // == w*512 + lane*8

    f32x4 acc[4][2] = {};

    for (int k0 = 0; k0 < K; k0 += 64) {
        __syncthreads();
#pragma unroll
        for (int i = 0; i < 2; ++i)
            gload16(pA + (size_t)(i * 32) * K + k0, &As[i * 2048 + ldst]);
#pragma unroll
        for (int i = 0; i < 4; ++i)
            gload16(pB + (size_t)(i * 32) * K + k0, &Bs[i * 2048 + ldst]);
        __syncthreads();
#pragma unroll
        for (int kk = 0; kk < 2; ++kk) {
            const int cofs = ((kk * 4 + g) ^ sw) * 8;
            bf16x8 af[4], bf[2];
#pragma unroll
            for (int mi = 0; mi < 4; ++mi) af[mi] = *(const bf16x8*)&As[(mi * 16 + lr) * 64 + cofs];
#pragma unroll
            for (int ni = 0; ni < 2; ++ni) bf[ni] = *(const bf16x8*)&Bs[(wn * 32 + ni * 16 + lr) * 64 + cofs];
#pragma unroll
            for (int mi = 0; mi < 4; ++mi)
#pragma unroll
                for (int ni = 0; ni < 2; ++ni)
                    acc[mi][ni] = mfma16(af[mi], bf[ni], acc[mi][ni]);
        }
    }

#pragma unroll
    for (int mi = 0; mi < 4; ++mi)
#pragma unroll
        for (int ni = 0; ni < 2; ++ni) {
            const int col = n0 + wn * 32 + ni * 16 + lr;
            const int row0 = m0 + mi * 16 + g * 4;
            const float bs = bias[col];
#pragma unroll
            for (int j = 0; j < 4; ++j)
                of[(size_t)(row0 + j) * 1024 + col] = acc[mi][ni][j] + bs;
        }
}

// ---------------- flash attention (causal): swapped QK^T, in-lane softmax, split-K ----------------
// Q,K: [32 bh][2048][64] bf16 (Q pre-scaled by log2e/8).  Vt: [32 bh][64][2048] bf16.
__global__ __launch_bounds__(256) void attn(const u16* __restrict__ Q, const u16* __restrict__ Kg,
                                            const u16* __restrict__ Vt, u16* __restrict__ O,
                                            u16* __restrict__ Opart, float* __restrict__ Mp,
                                            float* __restrict__ Lp, int do_split)
{
    __shared__ u16 Ks[64 * 64];          // 8 KB
    __shared__ u16 Vs[64 * 64];          // 8 KB
    __shared__ u16 Ps[4][16 * 64];       // 8 KB, per-wave P tile, chunk-swizzled

    const int bh = blockIdx.x;
    int qb, k_lo, k_hi, split;
    if (!do_split) {
        qb = 31 - (int)blockIdx.y; k_lo = 0; k_hi = qb + 1; split = -1;
    } else {
        const int y = (int)blockIdx.y;
        if (y < 32) {                    // split blocks dispatch first (heaviest work)
            qb = 16 + (y >> 1);
            split = y & 1;
            const int mid = (qb + 1) >> 1;
            k_lo = split ? mid : 0;
            k_hi = split ? qb + 1 : mid;
        } else {
            qb = 47 - y; k_lo = 0; k_hi = qb + 1; split = -1;
        }
    }
    const int q0 = qb * 64;
    const int t = threadIdx.x;
    const int w = t >> 6, lane = t & 63;
    const int g = lane >> 4, lr = lane & 15;
    const int qw = q0 + w * 16;
    const int sw = lr & 7;

    const u16* Qb = Q  + (size_t)bh * 2048 * 64;
    const u16* Kb = Kg + (size_t)bh * 2048 * 64;
    const u16* Vb = Vt + (size_t)bh * 64 * 2048;

    const bf16x8 qf0 = *(const bf16x8*)&Qb[(size_t)(qw + lr) * 64 + g * 8];
    const bf16x8 qf1 = *(const bf16x8*)&Qb[(size_t)(qw + lr) * 64 + 32 + g * 8];

    const short one = (short)0x3F80;                 // bf16 1.0
    const bf16x8 vones = {one, one, one, one, one, one, one, one};

    f32x4 oacc[4] = {};                              // C layout: q = qw + 4g+j, d = df*16+lr
    f32x4 lsacc = {};                                // row sums (P @ ones), same layout
    float mrun = -1e30f;                             // softmax state for q = qw + lr

    int bpaddr[4];
#pragma unroll
    for (int j = 0; j < 4; ++j) bpaddr[j] = (20 * g + j) * 4;

    const int pw_base = lr * 64;
    const int g2h = g >> 1;
    const int wic2 = (2 * g) & 3;

    bf16x8 kreg[2], vreg[2];
    const int srow0 = t >> 3, sch = t & 7;
    auto issue = [&](int kb) {
#pragma unroll
        for (int i = 0; i < 2; ++i) {
            const int row = srow0 + i * 32;
            kreg[i] = *(const bf16x8*)&Kb[(size_t)(kb * 64 + row) * 64 + sch * 8];
            vreg[i] = *(const bf16x8*)&Vb[(size_t)row * 2048 + kb * 64 + sch * 8];
        }
    };
    auto commit = [&]() {
#pragma unroll
        for (int i = 0; i < 2; ++i) {
            const int row = srow0 + i * 32;
            const int chs = sch ^ (row & 7);
            *(bf16x8*)&Ks[row * 64 + chs * 8] = kreg[i];
            *(bf16x8*)&Vs[row * 64 + chs * 8] = vreg[i];
        }
    };

    issue(k_lo);

    for (int kb = k_lo; kb < k_hi; ++kb) {
        const int k0 = kb * 64;
        __syncthreads();
        commit();
        __syncthreads();
        if (kb + 1 < k_hi) issue(kb + 1);

        f32x4 s[4] = {};
        __builtin_amdgcn_s_setprio(1);
#pragma unroll
        for (int ni = 0; ni < 4; ++ni) {
            const int row = ni * 16 + lr;
            bf16x8 kf0 = *(const bf16x8*)&Ks[row * 64 + (g ^ sw) * 8];
            bf16x8 kf1 = *(const bf16x8*)&Ks[row * 64 + ((4 + g) ^ sw) * 8];
            s[ni] = mfma16(kf0, qf0, s[ni]);
            s[ni] = mfma16(kf1, qf1, s[ni]);
        }
        __builtin_amdgcn_s_setprio(0);

        if (kb == qb) {
            const int qq = qw + lr;
#pragma unroll
            for (int ni = 0; ni < 4; ++ni)
#pragma unroll
                for (int j = 0; j < 4; ++j)
                    if (k0 + ni * 16 + g * 4 + j > qq) s[ni][j] = -1e30f;
        }

        float pm = fmaxf(fmaxf(fmaxf(s[0][0], s[0][1]), fmaxf(s[0][2], s[0][3])),
                         fmaxf(fmaxf(s[1][0], s[1][1]), fmaxf(s[1][2], s[1][3])));
        pm = fmaxf(pm, fmaxf(fmaxf(fmaxf(s[2][0], s[2][1]), fmaxf(s[2][2], s[2][3])),
                             fmaxf(fmaxf(s[3][0], s[3][1]), fmaxf(s[3][2], s[3][3]))));
        pm = fmaxf(pm, __shfl_xor(pm, 16));
        pm = fmaxf(pm, __shfl_xor(pm, 32));

        if (__any(pm > mrun + 8.f)) {
            const float mn = fmaxf(mrun, pm);
            const float r = __builtin_amdgcn_exp2f(mrun - mn);
            mrun = mn;
            const int ri = __float_as_int(r);
#pragma unroll
            for (int j = 0; j < 4; ++j) {
                const float ro = __int_as_float(__builtin_amdgcn_ds_bpermute(bpaddr[j], ri));
                lsacc[j] *= ro;
#pragma unroll
                for (int df = 0; df < 4; ++df) oacc[df][j] *= ro;
            }
        }

#pragma unroll
        for (int ni = 0; ni < 4; ++ni) {
            const int c8 = 2 * ni + g2h;
#pragma unroll
            for (int jp = 0; jp < 2; ++jp) {
                const float plo = __builtin_amdgcn_exp2f(s[ni][2 * jp]     - mrun);
                const float phi = __builtin_amdgcn_exp2f(s[ni][2 * jp + 1] - mrun);
                const u32 pr = (u32)f2bf_fast(plo) | ((u32)f2bf_fast(phi) << 16);
                const int wic = wic2 + jp;
                *(u32*)&Ps[w][pw_base + (c8 ^ sw) * 8 + wic * 2] = pr;
            }
        }
        // P is per-wave private: lgkmcnt (compiler) orders write->read, no barrier

        const bf16x8 p0 = *(const bf16x8*)&Ps[w][lr * 64 + (g ^ sw) * 8];
        const bf16x8 p1 = *(const bf16x8*)&Ps[w][lr * 64 + ((4 + g) ^ sw) * 8];
        __builtin_amdgcn_s_setprio(1);
        lsacc = mfma16(p0, vones, lsacc);
        lsacc = mfma16(p1, vones, lsacc);
#pragma unroll
        for (int df = 0; df < 4; ++df) {
            const int row = df * 16 + lr;
            bf16x8 vf0 = *(const bf16x8*)&Vs[row * 64 + (g ^ sw) * 8];
            bf16x8 vf1 = *(const bf16x8*)&Vs[row * 64 + ((4 + g) ^ sw) * 8];
            oacc[df] = mfma16(p0, vf0, oacc[df]);
            oacc[df] = mfma16(p1, vf1, oacc[df]);
        }
        __builtin_amdgcn_s_setprio(0);
    }

    if (split < 0) {
        // direct epilogue: normalize by MFMA row sums; store to [b][l][h*64+d]
        const int b = bh >> 4, h = bh & 15;
#pragma unroll
        for (int j = 0; j < 4; ++j) {
            const float inv = 1.f / lsacc[j];
            const int l = qw + g * 4 + j;
#pragma unroll
            for (int df = 0; df < 4; ++df)
                O[((size_t)b * 2048 + l) * 1024 + h * 64 + df * 16 + lr] = f2bf(oacc[df][j] * inv);
        }
    } else {
        // partial epilogue: bf16 NORMALIZED O + f32 per-row (m, l)
        u16* Ob = Opart + ((size_t)split * 32 + bh) * (1024 * 64);
        const int rb = qw - 1024 + 4 * g;            // block-relative row for (g,j)
#pragma unroll
        for (int j = 0; j < 4; ++j) {
            const float inv = 1.f / lsacc[j];
#pragma unroll
            for (int df = 0; df < 4; ++df)
                Ob[(size_t)(rb + j) * 64 + df * 16 + lr] = f2bf(oacc[df][j] * inv);
            if (lr == 0) Lp[(split * 32 + bh) * 1024 + rb + j] = lsacc[j];
        }
        if (g == 0)
            Mp[(split * 32 + bh) * 1024 + (qw - 1024) + lr] = mrun;
    }
}

// ---------------- merge of split-K partials (rows 1024..2047 of each bh) ----------------
__global__ __launch_bounds__(256) void attn_merge(const u16* __restrict__ Opart,
                                                  const float* __restrict__ Mp,
                                                  const float* __restrict__ Lp,
                                                  u16* __restrict__ O)
{
    const int idx = blockIdx.x * 256 + threadIdx.x;   // over 32*1024*64
    const int d  = idx & 63;
    const int rr = (idx >> 6) & 1023;
    const int bh = idx >> 16;
    const int si = bh * 1024 + rr;
    const float m0 = Mp[si], m1 = Mp[32 * 1024 + si];
    const float l0 = Lp[si], l1 = Lp[32 * 1024 + si];
    const float M  = fmaxf(m0, m1);
    const float v0 = __builtin_amdgcn_exp2f(m0 - M) * l0;
    const float v1 = __builtin_amdgcn_exp2f(m1 - M) * l1;
    const float o0 = bf2f(Opart[(size_t)si * 64 + d]);
    const float o1 = bf2f(Opart[(size_t)(32 * 1024 + si) * 64 + d]);
    const float o  = (v0 * o0 + v1 * o1) / (v0 + v1);
    const int b = bh >> 4, h = bh & 15;
    const int r = 1024 + rr;
    O[((size_t)b * 2048 + r) * 1024 + h * 64 + d] = f2bf(o);
}

// ---------------- launch ----------------

extern "C" void kernel_launch(void* const* d_in, const int* in_sizes, int n_in,
                              void* d_out, int out_size, void* d_ws, size_t ws_size,
                              hipStream_t stream)
{
    const float* hs = (const float*)d_in[0];
    const float* Wq = (const float*)d_in[1];
    const float* bq = (const float*)d_in[2];
    const float* Wk = (const float*)d_in[3];
    const float* bk = (const float*)d_in[4];
    const float* Wv = (const float*)d_in[5];
    const float* bv = (const float*)d_in[6];
    const float* Wo = (const float*)d_in[7];
    const float* bo = (const float*)d_in[8];
    float* out = (float*)d_out;

    char* ws = (char*)d_ws;
    u16*   Xbf   = (u16*)(ws);                     // 8 MB, reused as Abuf after QKV GEMM
    u16*   Wqkvt = (u16*)(ws + (8ull  << 20));     // 6 MB
    u16*   Wot   = (u16*)(ws + (14ull << 20));     // 2 MB
    float* bqkv  = (float*)(ws + (16ull << 20));   // 12 KB
    u16*   Qbuf  = (u16*)(ws + (17ull << 20));     // 8 MB
    u16*   Kbuf  = (u16*)(ws + (25ull << 20));     // 8 MB
    u16*   Vtbuf = (u16*)(ws + (33ull << 20));     // 8 MB
    u16*   Abuf  = Xbf;                            // alias: X dead after QKV GEMM
    u16*   Opart = (u16*)(ws + (42ull << 20));     // 8 MB  [2 splits][32 bh][1024 r][64 d] bf16
    float* Mpart = (float*)(ws + (58ull << 20));   // 256 KB [2][32][1024]
    float* Lpart = (float*)(ws + (58ull << 20) + (512ull << 10));   // 256 KB

    const int do_split = (ws_size >= (59ull << 20)) ? 1 : 0;

    cvt_x<<<4096, 256, 0, stream>>>(hs, Xbf, 4096 * 1024 / 4);
    transpose_w4<<<dim3(32, 32, 4), 256, 0, stream>>>(Wq, Wk, Wv, Wo, bq, bk, bv, Wqkvt, Wot, bqkv);

    // QKV: [4096 x 3072], 1D grid with XCD swizzle, runtime K
    gemm128_qkv<<<768, 256, 0, stream>>>(Xbf, Wqkvt, bqkv, Qbuf, Kbuf, Vtbuf, 1024);

    // attention: two-half split for heavy q-blocks when workspace allows
    if (do_split) {
        attn<<<dim3(32, 48), 256, 0, stream>>>(Qbuf, Kbuf, Vtbuf, Abuf, Opart, Mpart, Lpart, 1);
        attn_merge<<<8192, 256, 0, stream>>>(Opart, Mpart, Lpart, Abuf);
    } else {
        attn<<<dim3(32, 32), 256, 0, stream>>>(Qbuf, Kbuf, Vtbuf, Abuf, nullptr, nullptr, nullptr, 0);
    }

    // output projection: [4096 x 1024] -> fp32 d_out, 64x128 tile (512 blocks, 2/CU), runtime K
    gemm_o<<<dim3(8, 64), 256, 0, stream>>>(Abuf, Wot, bo, out, 1024);
}